// Round 14
// baseline (14814.281 us; speedup 1.0000x reference)
//
#include <hip/hip_runtime.h>
#include <math.h>

#define NWG 256
#define NTHR 512
static constexpr int S = 512, B = 64, I = 128, H = 512;

// ws layout (float units)
static constexpr size_t OFF_BUF0   = 0;                                  // S*B*H: x_proj -> out_pre in place
static constexpr size_t OFF_PCTX   = (size_t)S * B * H;                  // [64][4][520] pctx blocks (P2 h-exch unions here)
static constexpr size_t OFF_H3X    = OFF_PCTX + (size_t)64 * 4 * 520;    // [64][512] P3 h pieces
static constexpr size_t OFF_ACTR   = OFF_H3X + (size_t)64 * 512;         // [64][4][16] u32 pctx counters
static constexpr size_t OFF_HCTR   = OFF_ACTR + (size_t)64 * 4 * 16;     // [64][4][16] u32 h counters
static constexpr size_t OFF_GFLAGS = OFF_HCTR + (size_t)64 * 4 * 16;     // [256][16] u32 global barrier flags
static constexpr size_t OFF_END    = OFF_GFLAGS + (size_t)256 * 16;

typedef float f32x2 __attribute__((ext_vector_type(2)));
typedef float f32x4 __attribute__((ext_vector_type(4)));

// ---- coherent (sc0 sc1: die-level coherence point) ops ---------------------
// Each sc1 access is an uncoalesced line transaction: MINIMIZE COUNT.
// Wide (dwordx4) accesses from few threads; never redundant per-thread loads.
__device__ __forceinline__ void st_g4(float* p, f32x4 v) {
  asm volatile("global_store_dwordx4 %0, %1, off sc0 sc1" :: "v"(p), "v"(v) : "memory");
}
__device__ __forceinline__ void st_g2(float* p, f32x2 v) {
  asm volatile("global_store_dwordx2 %0, %1, off sc0 sc1" :: "v"(p), "v"(v) : "memory");
}
__device__ __forceinline__ void st_gu(unsigned* p, unsigned v) {
  asm volatile("global_store_dword %0, %1, off sc0 sc1" :: "v"(p), "v"(v) : "memory");
}
__device__ __forceinline__ f32x4 ld_g4(const float* p) {
  f32x4 v;
  asm volatile("global_load_dwordx4 %0, %1, off sc0 sc1\n\ts_waitcnt vmcnt(0)"
               : "=&v"(v) : "v"(p) : "memory");
  return v;
}
__device__ __forceinline__ void ld3_g4(const float* p0, const float* p1, const float* p2,
                                       f32x4& a, f32x4& b, f32x4& c) {
  asm volatile("global_load_dwordx4 %0, %3, off sc0 sc1\n\t"
               "global_load_dwordx4 %1, %4, off sc0 sc1\n\t"
               "global_load_dwordx4 %2, %5, off sc0 sc1\n\t"
               "s_waitcnt vmcnt(0)"
               : "=&v"(a), "=&v"(b), "=&v"(c)
               : "v"(p0), "v"(p1), "v"(p2) : "memory");
}
__device__ __forceinline__ void ld3_g2(const float* p0, const float* p1, const float* p2,
                                       f32x2& a, f32x2& b, f32x2& c) {
  asm volatile("global_load_dwordx2 %0, %3, off sc0 sc1\n\t"
               "global_load_dwordx2 %1, %4, off sc0 sc1\n\t"
               "global_load_dwordx2 %2, %5, off sc0 sc1\n\t"
               "s_waitcnt vmcnt(0)"
               : "=&v"(a), "=&v"(b), "=&v"(c)
               : "v"(p0), "v"(p1), "v"(p2) : "memory");
}
__device__ __forceinline__ void poll3_ge(const unsigned* p0, const unsigned* p1,
                                         const unsigned* p2, unsigned tgt) {
  unsigned a, b, c;
  do {
    asm volatile("global_load_dword %0, %3, off sc0 sc1\n\t"
                 "global_load_dword %1, %4, off sc0 sc1\n\t"
                 "global_load_dword %2, %5, off sc0 sc1\n\t"
                 "s_waitcnt vmcnt(0)"
                 : "=&v"(a), "=&v"(b), "=&v"(c)
                 : "v"(p0), "v"(p1), "v"(p2) : "memory");
  } while (a < tgt || b < tgt || c < tgt);
}
__device__ __forceinline__ void vm_drain() { asm volatile("s_waitcnt vmcnt(0)" ::: "memory"); }

__device__ __forceinline__ void gbar_all(unsigned* gflags, int wg, unsigned gen) {
  __syncthreads();
  if (threadIdx.x == 0)
    __hip_atomic_store(gflags + (size_t)wg * 16, gen, __ATOMIC_RELEASE, __HIP_MEMORY_SCOPE_AGENT);
  if (threadIdx.x < 256) {
    while (__hip_atomic_load(gflags + (size_t)threadIdx.x * 16, __ATOMIC_ACQUIRE,
                             __HIP_MEMORY_SCOPE_AGENT) < gen) {}
  }
  __syncthreads();
}

// LDS arena (floats). P1 uses [0,8192) as tile; P2/P3 overlay:
static constexpr int L_MRG  = 0;      // 3a: 8x512 merge | 3c: peer payloads [0,512),[512,1024),[1024,1536)
static constexpr int L_ML   = 4096;   // 3a: 8x(m,l) | 3c: 3 peer (m,l) pairs (reused)
static constexpr int L_H    = 4112;   // 512 current h
static constexpr int L_CTX  = 4624;   // 512 own csum -> cval
static constexpr int L_HSTG = 5136;   // 128 hnew staging
// total 5264 floats = 21 KB (P1 tile 8192 = 32 KB dominates)

__global__ __launch_bounds__(NTHR)
void attn_fused(
    const float* __restrict__ inputs,
    const float* __restrict__ Wih_pre, const float* __restrict__ Whh_pre,
    const float* __restrict__ bih_pre, const float* __restrict__ bhh_pre,
    const float* __restrict__ Wih_post, const float* __restrict__ Whh_post,
    const float* __restrict__ bih_post, const float* __restrict__ bhh_post,
    const float* __restrict__ Wfc, const float* __restrict__ bfc,
    float* __restrict__ out, float* __restrict__ ws)
{
  float* buf0  = ws + OFF_BUF0;
  float* pctxg = ws + OFF_PCTX;
  float* h3xg  = ws + OFF_H3X;
  unsigned* actrg  = (unsigned*)(ws + OFF_ACTR);
  unsigned* hctrg  = (unsigned*)(ws + OFF_HCTR);
  unsigned* gflags = (unsigned*)(ws + OFF_GFLAGS);

  const int wg   = blockIdx.x;
  const int tid  = threadIdx.x;
  const int lane = tid & 63;
  const int wv   = tid >> 6;
  const int b    = wg & 63;
  const int part = wg >> 6;
  const int q1 = (part + 1) & 3, q2 = (part + 2) & 3, q3 = (part + 3) & 3;

  unsigned* hc_own = hctrg + ((size_t)b * 4 + part) * 16;
  unsigned* hc1 = hctrg + ((size_t)b * 4 + q1) * 16;
  unsigned* hc2 = hctrg + ((size_t)b * 4 + q2) * 16;
  unsigned* hc3 = hctrg + ((size_t)b * 4 + q3) * 16;
  unsigned* ac_own = actrg + ((size_t)b * 4 + part) * 16;
  unsigned* ac1 = actrg + ((size_t)b * 4 + q1) * 16;
  unsigned* ac2 = actrg + ((size_t)b * 4 + q2) * 16;
  unsigned* ac3 = actrg + ((size_t)b * 4 + q3) * 16;

  __shared__ __align__(16) float smem[8192];

  // ================= P1: x_proj = inputs @ W_ih_pre^T + (b_ih+b_hh) ==========
  {
    const int h = tid;
    f32x4 Wr[32];
    const f32x4* wrow = (const f32x4*)(Wih_pre + (size_t)h * I);
    #pragma unroll
    for (int c = 0; c < 32; ++c) Wr[c] = wrow[c];
    const float bias = bih_pre[h] + bhh_pre[h];
    const int r0 = wg * 128;
    for (int t2 = 0; t2 < 2; ++t2) {
      __syncthreads();
      const f32x4* src = (const f32x4*)(inputs + (size_t)(r0 + t2 * 64) * I);
      for (int idx = tid; idx < 64 * I / 4; idx += NTHR)
        ((f32x4*)smem)[idx] = src[idx];
      __syncthreads();
      for (int r = 0; r < 64; ++r) {
        const f32x4* arow = (const f32x4*)(smem + r * I);
        float acc0 = 0.f, acc1 = 0.f;
        #pragma unroll
        for (int c = 0; c < 32; c += 2) {
          f32x4 a0 = arow[c], a1 = arow[c + 1];
          acc0 += a0.x * Wr[c].x + a0.y * Wr[c].y + a0.z * Wr[c].z + a0.w * Wr[c].w;
          acc1 += a1.x * Wr[c+1].x + a1.y * Wr[c+1].y + a1.z * Wr[c+1].z + a1.w * Wr[c+1].w;
        }
        buf0[(size_t)(r0 + t2 * 64 + r) * H + h] = acc0 + acc1 + bias;
      }
    }
  }
  gbar_all(gflags, wg, 1u);

  // ================= P2: pre-RNN, 512 steps, per-batch (4 WGs) ==============
  const int j  = part * 128 + (tid >> 2);
  const int kq = tid & 3;
  {
    const f32x4* wrow = (const f32x4*)(Whh_pre + (size_t)j * H);
    float* hst = smem + L_H;
    hst[tid] = 0.f;
    __syncthreads();

    for (int t = 0; t < S; ++t) {
      float* brow = buf0 + ((size_t)t * B + b) * H;
      float xp = brow[j];
      const f32x4* hst4 = (const f32x4*)hst;
      float d = 0.f;
      #pragma unroll
      for (int i = 0; i < 32; ++i) {
        f32x4 w = wrow[4 * i + kq];      // streamed (L1/L2-hit)
        f32x4 hv = hst4[4 * i + kq];     // 4 addrs, broadcast: conflict-free
        d += w.x * hv.x + w.y * hv.y + w.z * hv.z + w.w * hv.w;
      }
      d += __shfl_xor(d, 1);
      d += __shfl_xor(d, 2);
      float hnew = tanhf(xp + d);
      const int par = (t + 1) & 1;
      float* slotbase = pctxg + (((size_t)b * 2 + par) * 4) * 128;
      if (kq == 0) {
        brow[j] = hnew;                      // out_pre in place (read after gbar)
        smem[L_HSTG + (tid >> 2)] = hnew;    // stage for wide publish
      }
      __syncthreads();
      if (tid < 32) {                        // 32 x dwordx4 publish (vs 128 scalar)
        f32x4 v = *(const f32x4*)(smem + L_HSTG + 4 * tid);
        st_g4(slotbase + (size_t)part * 128 + 4 * tid, v);
      }
      vm_drain();
      __syncthreads();
      if (tid == 0) {
        st_gu(hc_own, (unsigned)(t + 1));
        poll3_ge(hc1, hc2, hc3, (unsigned)(t + 1));
      }
      __syncthreads();
      if (tid < 128) {
        f32x4 hv = ld_g4(slotbase + (size_t)tid * 4);
        ((f32x4*)hst)[tid] = hv;
      }
      __syncthreads();
    }
  }
  gbar_all(gflags, wg, 2u);

  // ---- G strip: plain C++ loads; 128 floats/thread resident (round-2 proof) -
  f32x4 ga[16], gb[16];
  {
    const int s0 = part * 128 + wv * 16;
    #pragma unroll
    for (int i = 0; i < 16; ++i) {
      const float* row = buf0 + ((size_t)(s0 + i) * B + b) * H;
      ga[i] = *(const f32x4*)(row + lane * 4);
      gb[i] = *(const f32x4*)(row + 256 + lane * 4);
    }
  }

  // W_post rows streamed from L2 every step (2 MB shared per XCD)
  const f32x4* wihr = (const f32x4*)(Wih_post + (size_t)j * H);
  const f32x4* whhr = (const f32x4*)(Whh_post + (size_t)j * H);
  const float bp3 = bih_post[j] + bhh_post[j];

  float* blk_own = pctxg + ((size_t)b * 4 + part) * 520;
  float* blk1 = pctxg + ((size_t)b * 4 + q1) * 520;
  float* blk2 = pctxg + ((size_t)b * 4 + q2) * 520;
  float* blk3 = pctxg + ((size_t)b * 4 + q3) * 520;

  smem[L_H + tid] = 0.f;   // attention h_0 = 0
  __syncthreads();

  // ================= P3: attention loop, 512 steps, per-batch ================
  for (int u = 0; u < H; ++u) {
    // ---- 3a: scores + softmax partials + ctx partial (registers) ----
    float mstar, lsum;
    {
      f32x4 h0v = ((const f32x4*)(smem + L_H))[lane];
      f32x4 h1v = ((const f32x4*)(smem + L_H))[64 + lane];
      float p[16];
      #pragma unroll
      for (int i = 0; i < 16; ++i)
        p[i] = ga[i].x * h0v.x + ga[i].y * h0v.y + ga[i].z * h0v.z + ga[i].w * h0v.w
             + gb[i].x * h1v.x + gb[i].y * h1v.y + gb[i].z * h1v.z + gb[i].w * h1v.w;
      #pragma unroll
      for (int off = 32; off > 0; off >>= 1) {
        #pragma unroll
        for (int i = 0; i < 16; ++i) p[i] += __shfl_xor(p[i], off);
      }
      float m = p[0];
      #pragma unroll
      for (int i = 1; i < 16; ++i) m = fmaxf(m, p[i]);
      float l = 0.f;
      f32x4 c0 = {0.f,0.f,0.f,0.f}, c1 = {0.f,0.f,0.f,0.f};
      #pragma unroll
      for (int i = 0; i < 16; ++i) {
        float e = __expf(p[i] - m);
        l += e;
        c0 += e * ga[i];
        c1 += e * gb[i];
      }
      float* ctx_lds = smem + L_MRG;
      float* ml_lds  = smem + L_ML;
      *(f32x4*)(ctx_lds + wv * 512 + lane * 4)       = c0;
      *(f32x4*)(ctx_lds + wv * 512 + 256 + lane * 4) = c1;
      if (lane == 0) { ml_lds[wv * 2] = m; ml_lds[wv * 2 + 1] = l; }
      __syncthreads();
      mstar = ml_lds[0];
      #pragma unroll
      for (int w = 1; w < 8; ++w) mstar = fmaxf(mstar, ml_lds[w * 2]);
      lsum = 0.f;
      float csum = 0.f;
      #pragma unroll
      for (int w = 0; w < 8; ++w) {
        float sc = __expf(ml_lds[w * 2] - mstar);
        lsum += sc * ml_lds[w * 2 + 1];
        csum += sc * ctx_lds[w * 512 + tid];
      }
      smem[L_CTX + tid] = csum;            // own partial stays local
      __syncthreads();
      if (tid < 128) {                     // 128 x dwordx4 publish (vs 512 scalar)
        f32x4 v = *(const f32x4*)(smem + L_CTX + 4 * tid);
        st_g4(blk_own + 4 * tid, v);
      } else if (tid == 128) {
        st_g2(blk_own + 512, f32x2{mstar, lsum});
      }
      vm_drain();
      __syncthreads();
      if (tid == 0) st_gu(ac_own, (unsigned)(u + 1));
    }

    // ---- z2 = Whh_post(row j) . h : streamed from L2 WHILE peers finish 3a
    float zacc = 0.f;
    {
      const f32x4* h4 = (const f32x4*)(smem + L_H);
      #pragma unroll
      for (int i = 0; i < 32; ++i) {
        f32x4 w = whhr[4 * i + kq];
        f32x4 hv = h4[4 * i + kq];
        zacc += w.x * hv.x + w.y * hv.y + w.z * hv.z + w.w * hv.w;
      }
    }

    // ---- 3c: merge partials -> ctx; wih GEMV streamed; h-update ----
    {
      if (tid == 0) poll3_ge(ac1, ac2, ac3, (unsigned)(u + 1));
      __syncthreads();
      // coalesced peer fetch into LDS: 3x128 dwordx4 + 3 ml pairs ONCE
      if (tid < 128) {
        f32x4 a, bb, c;
        ld3_g4(blk1 + 4 * tid, blk2 + 4 * tid, blk3 + 4 * tid, a, bb, c);
        *(f32x4*)(smem + L_MRG + 4 * tid)        = a;
        *(f32x4*)(smem + L_MRG + 512 + 4 * tid)  = bb;
        *(f32x4*)(smem + L_MRG + 1024 + 4 * tid) = c;
      } else if (tid == 128) {
        f32x2 x, y, z;
        ld3_g2(blk1 + 512, blk2 + 512, blk3 + 512, x, y, z);
        smem[L_ML + 0] = x.x; smem[L_ML + 1] = x.y;
        smem[L_ML + 2] = y.x; smem[L_ML + 3] = y.y;
        smem[L_ML + 4] = z.x; smem[L_ML + 5] = z.y;
      }
      __syncthreads();
      float m1v = smem[L_ML + 0], l1v = smem[L_ML + 1];
      float m2v = smem[L_ML + 2], l2v = smem[L_ML + 3];
      float m3v = smem[L_ML + 4], l3v = smem[L_ML + 5];
      float mb = fmaxf(fmaxf(mstar, m1v), fmaxf(m2v, m3v));
      float s0 = __expf(mstar - mb), s1 = __expf(m1v - mb);
      float s2 = __expf(m2v - mb), s3 = __expf(m3v - mb);
      float inv = 1.0f / (s0 * lsum + s1 * l1v + s2 * l2v + s3 * l3v);
      float cval = (s0 * smem[L_CTX + tid] + s1 * smem[L_MRG + tid] +
                    s2 * smem[L_MRG + 512 + tid] + s3 * smem[L_MRG + 1024 + tid]) * inv;
      smem[L_CTX + tid] = cval;          // own slot read->write, no cross-thread hazard
      __syncthreads();
      const f32x4* ctx4 = (const f32x4*)(smem + L_CTX);
      float acc = zacc;
      #pragma unroll
      for (int i = 0; i < 32; ++i) {
        f32x4 w = wihr[4 * i + kq];      // streamed from L2
        f32x4 cv = ctx4[4 * i + kq];     // broadcast, conflict-free
        acc += w.x * cv.x + w.y * cv.y + w.z * cv.z + w.w * cv.w;
      }
      acc += __shfl_xor(acc, 1);
      acc += __shfl_xor(acc, 2);
      float hnew = tanhf(acc + bp3);
      if (kq == 0) smem[L_HSTG + (tid >> 2)] = hnew;   // stage for wide publish
      __syncthreads();
      if (tid < 32) {                    // 32 x dwordx4 publish (vs 128 scalar)
        f32x4 v = *(const f32x4*)(smem + L_HSTG + 4 * tid);
        st_g4(h3xg + (size_t)b * 512 + part * 128 + 4 * tid, v);
      }
      vm_drain();
      __syncthreads();
      if (tid == 0) {
        st_gu(hc_own, (unsigned)(513 + u));
        poll3_ge(hc1, hc2, hc3, (unsigned)(513 + u));
      }
      __syncthreads();
      if (tid < 128) {
        f32x4 hv = ld_g4(h3xg + (size_t)b * 512 + (size_t)tid * 4);
        ((f32x4*)(smem + L_H))[tid] = hv;
      }
      __syncthreads();
    }
  }

  // ================= final: out = h_post @ W_fc^T + b_fc =====================
  if (part == 0) {
    float pv = smem[L_H + tid] * Wfc[tid];
    #pragma unroll
    for (int off = 32; off > 0; off >>= 1) pv += __shfl_xor(pv, off);
    __syncthreads();
    if (lane == 0) smem[L_ML + wv] = pv;
    __syncthreads();
    if (tid == 0) {
      float s = 0.f;
      #pragma unroll
      for (int w = 0; w < 8; ++w) s += smem[L_ML + w];
      out[b] = s + bfc[0];
    }
  }
}

extern "C" void kernel_launch(void* const* d_in, const int* in_sizes, int n_in,
                              void* d_out, int out_size, void* d_ws, size_t ws_size,
                              hipStream_t stream) {
  (void)in_sizes; (void)n_in; (void)out_size; (void)ws_size;
  const float* inputs   = (const float*)d_in[0];
  const float* Wih_pre  = (const float*)d_in[1];
  const float* Whh_pre  = (const float*)d_in[2];
  const float* bih_pre  = (const float*)d_in[3];
  const float* bhh_pre  = (const float*)d_in[4];
  const float* Wih_post = (const float*)d_in[5];
  const float* Whh_post = (const float*)d_in[6];
  const float* bih_post = (const float*)d_in[7];
  const float* bhh_post = (const float*)d_in[8];
  const float* Wfc      = (const float*)d_in[9];
  const float* bfc      = (const float*)d_in[10];
  float* out = (float*)d_out;
  float* ws  = (float*)d_ws;

  // Zero counters + global barrier flags every launch (graph-replay safe).
  hipMemsetAsync((char*)d_ws + OFF_ACTR * sizeof(float), 0,
                 (OFF_END - OFF_ACTR) * sizeof(float), stream);

  attn_fused<<<dim3(NWG), dim3(NTHR), 0, stream>>>(
      inputs, Wih_pre, Whh_pre, bih_pre, bhh_pre,
      Wih_post, Whh_post, bih_post, bhh_post, Wfc, bfc, out, ws);
}